// Round 14
// baseline (47.356 us; speedup 1.0000x reference)
//
#include <hip/hip_runtime.h>
#include <cfloat>
#include <cmath>

#define F_   8
#define H_   24
#define W_   24
#define NTOK 4608
#define NSEQ 4609
#define MPAD 4736           // 37*128 = 74*64
#define DIM  512
#define QKVC 1536           // q | k | v
#define NNB  28
#define SCALEF 0.125f

typedef unsigned short ushort_t;
typedef __attribute__((ext_vector_type(8))) short short8v;
typedef __attribute__((ext_vector_type(8))) unsigned short ushort8v;
typedef __attribute__((ext_vector_type(4))) float floatx4;
typedef __attribute__((ext_vector_type(2))) float floatx2;
typedef __attribute__((ext_vector_type(4))) unsigned int uint4v;

typedef const __attribute__((address_space(1))) unsigned int guint_t;
typedef __attribute__((address_space(3))) unsigned int luint_t;

__device__ __forceinline__ float bf2f(unsigned short u) {
    return __uint_as_float(((unsigned)u) << 16);
}
__device__ __forceinline__ unsigned short f2bf(float f) {
    unsigned u = __float_as_uint(f);
    unsigned r = (u + 0x7FFFu + ((u >> 16) & 1u)) >> 16;
    return (unsigned short)r;
}
// unpack u32 holding 2 bf16 (lo,hi) -> float2 {lo<<16, hi&0xffff0000}
__device__ __forceinline__ floatx2 up2(unsigned w) {
    floatx2 r;
    r.x = __uint_as_float(w << 16);
    r.y = __uint_as_float(w & 0xffff0000u);
    return r;
}

// ---------------------------------------------------------------------------
// Fused conversion (round-9 known-good):
//  blocks [0, XBLK):        x(f32) -> xb(bf16), rows zero-padded to MPAD
//  blocks [XBLK, XBLK+192): [w_q | w_kv] -> wcatT (bf16, [1536][512])
//  blocks [XBLK+192, +64):  w_out -> woutT (bf16, [512][512])
// ---------------------------------------------------------------------------
#define XBLK 1184                      // MPAD*512/2048
#define CONV_BLOCKS (XBLK + 192 + 64)

__global__ __launch_bounds__(256) void conv_k(
    const float* __restrict__ x, const float* __restrict__ wq,
    const float* __restrict__ wkv, const float* __restrict__ wout,
    ushort_t* __restrict__ xb, ushort_t* __restrict__ wcatT,
    ushort_t* __restrict__ woutT)
{
    const int bid = blockIdx.x, tid = threadIdx.x;
    __shared__ ushort_t tile[64][72];

    if (bid < XBLK) {
        int e0 = (bid * 256 + tid) * 8;
        int row = e0 >> 9;
        float4 a = make_float4(0.f, 0.f, 0.f, 0.f);
        float4 b = make_float4(0.f, 0.f, 0.f, 0.f);
        if (row < NSEQ) {
            a = *reinterpret_cast<const float4*>(&x[e0]);
            b = *reinterpret_cast<const float4*>(&x[e0 + 4]);
        }
        ushort8v o;
        o[0] = f2bf(a.x); o[1] = f2bf(a.y); o[2] = f2bf(a.z); o[3] = f2bf(a.w);
        o[4] = f2bf(b.x); o[5] = f2bf(b.y); o[6] = f2bf(b.z); o[7] = f2bf(b.w);
        *reinterpret_cast<ushort8v*>(&xb[e0]) = o;
        return;
    }

    int blk2 = bid - XBLK;
    const float* src; int ld, cb; ushort_t* dst; int k0;
    if (blk2 < 192) {
        int nt = blk2 >> 3, kt = blk2 & 7;
        int n0 = nt * 64;
        if (n0 < 512) { src = wq;  ld = 512;  cb = n0; }
        else          { src = wkv; ld = 1024; cb = n0 - 512; }
        dst = wcatT + (size_t)n0 * 512;
        k0 = kt * 64;
    } else {
        int b3 = blk2 - 192;
        int nt = b3 >> 3, kt = b3 & 7;
        src = wout; ld = 512; cb = nt * 64;
        dst = woutT + (size_t)(nt * 64) * 512;
        k0 = kt * 64;
    }

    {
        int r = tid >> 4, c4 = (tid & 15) * 4;
        #pragma unroll
        for (int p = 0; p < 4; ++p) {
            int rr = r + p * 16;
            float4 v = *reinterpret_cast<const float4*>(&src[(size_t)(k0 + rr) * ld + cb + c4]);
            tile[c4 + 0][rr] = f2bf(v.x);
            tile[c4 + 1][rr] = f2bf(v.y);
            tile[c4 + 2][rr] = f2bf(v.z);
            tile[c4 + 3][rr] = f2bf(v.w);
        }
    }
    __syncthreads();
    {
        int nl = tid >> 3, ks = (tid & 7) * 8;
        #pragma unroll
        for (int rep = 0; rep < 2; ++rep) {
            int nn = nl + rep * 32;
            ushort8v vv = *reinterpret_cast<const ushort8v*>(&tile[nn][ks]);
            *reinterpret_cast<ushort8v*>(&dst[(size_t)nn * 512 + k0 + ks]) = vv;
        }
    }
}

// ---------------------------------------------------------------------------
// bf16 MFMA GEMM, single-buffered, templated on BM/BN/BK.
// BK=128 for gemm_qkv: 4 K-steps (half the barrier drains), 48 KB LDS ->
// 3 blocks/CU. BK=64 for gemm_out (round-12 known-good).
// Staging: TPR = BK/8 threads per row, each 16B; gs = slot ^ (r&7)
// (XOR of low 3 bits, bijective for any TPR >= 8, 8-way bank spread).
// XCD-chunked bijective block swizzle.
// ---------------------------------------------------------------------------
template<int BM, int BN, int BK, bool F32OUT>
__global__ __launch_bounds__(256, (BK == 128 ? 3 : 4)) void gemm_k(
    const ushort_t* __restrict__ A,    // [MPAD][512] bf16
    const ushort_t* __restrict__ BT,   // [N][512] bf16
    const float* __restrict__ bias,
    void* __restrict__ Cv, int ldc)
{
    __shared__ ushort_t sA[BM * BK];
    __shared__ ushort_t sB[BN * BK];
    const int tid = threadIdx.x;

    const int nwg = gridDim.x * gridDim.y;
    const int orig = blockIdx.y * gridDim.x + blockIdx.x;
    const int xcd = orig & 7;
    const int qq = nwg >> 3, rr8 = nwg & 7;
    const int wg = (xcd < rr8 ? xcd * (qq + 1) : rr8 * (qq + 1) + (xcd - rr8) * qq)
                   + (orig >> 3);
    const int row0 = (wg / gridDim.x) * BM;
    const int col0 = (wg % gridDim.x) * BN;

    constexpr int NWC = BN / 64;       // wave-cols
    constexpr int NWR = 4 / NWC;       // wave-rows
    constexpr int WROWS = BM / NWR;    // rows per wave
    constexpr int MR = WROWS / 16;     // m-fragments per wave
    constexpr int TPR = BK / 8;        // staging threads per row
    constexpr int RPR = 256 / TPR;     // rows per staging round

    const int wid = tid >> 6, lane = tid & 63;
    const int wr = wid / NWC, wc = wid % NWC;
    const int l15 = lane & 15, kp = lane >> 4;

    floatx4 acc[MR][4];
    #pragma unroll
    for (int m = 0; m < MR; ++m)
        #pragma unroll
        for (int n = 0; n < 4; ++n)
            acc[m][n] = (floatx4){0.f, 0.f, 0.f, 0.f};

    const ushort_t* Abase = A + (size_t)row0 * 512;
    const ushort_t* Bbase = BT + (size_t)col0 * 512;

    for (int kt = 0; kt < 512 / BK; ++kt) {
        const int k0 = kt * BK;
        #pragma unroll
        for (int rnd = 0; rnd < BM / RPR; ++rnd) {
            int r = rnd * RPR + tid / TPR;
            int slot = tid % TPR;
            int gs = slot ^ (r & 7);
            __builtin_amdgcn_global_load_lds(
                (guint_t*)(Abase + (size_t)r * 512 + k0 + gs * 8),
                (luint_t*)(sA + r * BK + slot * 8), 16, 0, 0);
        }
        #pragma unroll
        for (int rnd = 0; rnd < BN / RPR; ++rnd) {
            int r = rnd * RPR + tid / TPR;
            int slot = tid % TPR;
            int gs = slot ^ (r & 7);
            __builtin_amdgcn_global_load_lds(
                (guint_t*)(Bbase + (size_t)r * 512 + k0 + gs * 8),
                (luint_t*)(sB + r * BK + slot * 8), 16, 0, 0);
        }
        __syncthreads();

        #pragma unroll
        for (int kk = 0; kk < BK / 32; ++kk) {
            short8v af[MR], bfr[4];
            #pragma unroll
            for (int m = 0; m < MR; ++m) {
                int r = wr * WROWS + m * 16 + l15;
                int slot = kk * 4 + kp;
                af[m] = *(const short8v*)&sA[r * BK + ((slot ^ (r & 7)) << 3)];
            }
            #pragma unroll
            for (int n = 0; n < 4; ++n) {
                int r = wc * 64 + n * 16 + l15;
                int slot = kk * 4 + kp;
                bfr[n] = *(const short8v*)&sB[r * BK + ((slot ^ (r & 7)) << 3)];
            }
            #pragma unroll
            for (int m = 0; m < MR; ++m)
                #pragma unroll
                for (int n = 0; n < 4; ++n)
                    acc[m][n] = __builtin_amdgcn_mfma_f32_16x16x32_bf16(
                        af[m], bfr[n], acc[m][n], 0, 0, 0);
        }
        __syncthreads();
    }

    if (!F32OUT) {
        ushort_t* C = (ushort_t*)Cv;
        #pragma unroll
        for (int m = 0; m < MR; ++m) {
            int rb = row0 + wr * WROWS + m * 16 + kp * 4;
            #pragma unroll
            for (int n = 0; n < 4; ++n) {
                int col = col0 + wc * 64 + n * 16 + l15;
                #pragma unroll
                for (int q = 0; q < 4; ++q)
                    C[(size_t)(rb + q) * ldc + col] = f2bf(acc[m][n][q]);
            }
        }
    } else {
        float* C = (float*)Cv;
        #pragma unroll
        for (int m = 0; m < MR; ++m) {
            int rb = row0 + wr * WROWS + m * 16 + kp * 4;
            #pragma unroll
            for (int n = 0; n < 4; ++n) {
                int col = col0 + wc * 64 + n * 16 + l15;
                float bv = bias[col];
                #pragma unroll
                for (int q = 0; q < 4; ++q)
                    if (rb + q < NSEQ)
                        C[(size_t)(rb + q) * ldc + col] = acc[m][n][q] + bv;
            }
        }
    }
}

// ---------------------------------------------------------------------------
// Attention, wave-per-token (round-13 known-good): packed-fp32 math,
// chunked batched K loads, V chunk-1 prefetch under softmax, hoisted PV
// broadcasts, __launch_bounds__(256,4), XCD-chunked block swizzle.
// ---------------------------------------------------------------------------
__global__ __launch_bounds__(256, 4) void attn_k(
    const ushort_t* __restrict__ qkv,
    const float* __restrict__ wtalk,
    ushort_t* __restrict__ outh)
{
    const int lane = threadIdx.x & 63;
    const int bid0 = blockIdx.x;                            // 1152 = 8*144
    const int bswz = (bid0 & 7) * (gridDim.x >> 3) + (bid0 >> 3);
    const int i = bswz * 4 + (threadIdx.x >> 6);
    const int h = lane >> 3, s = lane & 7;

    const int t = i / (H_ * W_), rem = i % (H_ * W_);
    const int yy = rem / W_, xx = rem % W_;

    int rowj = -1;
    if (lane == 0) rowj = 0;
    else if (lane < NNB) {
        int e = lane - 1;
        int dt = e / 9 - 1, dy = (e / 3) % 3 - 1, dx = e % 3 - 1;
        int nt = t + dt, ny = yy + dy, nx = xx + dx;
        bool valid = ((unsigned)nt < (unsigned)F_) && ((unsigned)ny < (unsigned)H_) &&
                     ((unsigned)nx < (unsigned)W_);
        int u = (nt * H_ + ny) * W_ + nx;
        rowj = (valid && u <= i) ? (u + 1) : -1;
    }

    // clamped row table for loads (masked -> row 0)
    int rows[NNB];
    #pragma unroll
    for (int j = 0; j < NNB; ++j) {
        int r = __shfl(rowj, j, 64);
        rows[j] = r < 0 ? 0 : r;
    }

    // q as 4 packed float2 pairs
    floatx2 qf2[4];
    {
        uint4v qv = *(const uint4v*)&qkv[(size_t)(i + 1) * QKVC + lane * 8];
        #pragma unroll
        for (int p = 0; p < 4; ++p) qf2[p] = up2(qv[p]);
    }

    // ---- K dots, chunked 12/12/4 (batched loads, packed fma) ----
    float ps[NNB];
    {
        uint4v kc[12];
        #pragma unroll
        for (int j = 0; j < 12; ++j)
            kc[j] = *(const uint4v*)&qkv[(size_t)rows[j] * QKVC + 512 + lane * 8];
        #pragma unroll
        for (int j = 0; j < 12; ++j) {
            floatx2 a2 = (floatx2){0.f, 0.f};
            #pragma unroll
            for (int p = 0; p < 4; ++p)
                a2 = __builtin_elementwise_fma(qf2[p], up2(kc[j][p]), a2);
            ps[j] = a2.x + a2.y;
        }
        #pragma unroll
        for (int j = 12; j < 24; ++j)
            kc[j - 12] = *(const uint4v*)&qkv[(size_t)rows[j] * QKVC + 512 + lane * 8];
        #pragma unroll
        for (int j = 12; j < 24; ++j) {
            floatx2 a2 = (floatx2){0.f, 0.f};
            #pragma unroll
            for (int p = 0; p < 4; ++p)
                a2 = __builtin_elementwise_fma(qf2[p], up2(kc[j - 12][p]), a2);
            ps[j] = a2.x + a2.y;
        }
        uint4v kt_[4];
        #pragma unroll
        for (int j = 24; j < 28; ++j)
            kt_[j - 24] = *(const uint4v*)&qkv[(size_t)rows[j] * QKVC + 512 + lane * 8];
        #pragma unroll
        for (int j = 24; j < 28; ++j) {
            floatx2 a2 = (floatx2){0.f, 0.f};
            #pragma unroll
            for (int p = 0; p < 4; ++p)
                a2 = __builtin_elementwise_fma(qf2[p], up2(kt_[j - 24][p]), a2);
            ps[j] = a2.x + a2.y;
        }
    }

    // ---- V chunk-1 prefetch: in flight across reduce/softmax/TH ----
    uint4v vc[12];
    #pragma unroll
    for (int j = 0; j < 12; ++j)
        vc[j] = *(const uint4v*)&qkv[(size_t)rows[j] * QKVC + 1024 + lane * 8];

    // ---- reduce-scatter (xor 1,2,4) ----
    float v1[14];
    {
        bool hi = (s & 1) != 0;
        #pragma unroll
        for (int m = 0; m < 14; ++m) {
            float keep = hi ? ps[2 * m + 1] : ps[2 * m];
            float oth  = hi ? ps[2 * m]     : ps[2 * m + 1];
            v1[m] = keep + __shfl_xor(oth, 1, 64);
        }
    }
    float v2[8];
    {
        bool hi = (s & 2) != 0;
        #pragma unroll
        for (int m = 0; m < 7; ++m) {
            float keep = hi ? v1[2 * m + 1] : v1[2 * m];
            float oth  = hi ? v1[2 * m]     : v1[2 * m + 1];
            v2[m] = keep + __shfl_xor(oth, 2, 64);
        }
        v2[7] = 0.f;
    }
    float simk[4];
    {
        bool hi = (s & 4) != 0;
        #pragma unroll
        for (int k = 0; k < 4; ++k) {
            float keep = hi ? v2[2 * k + 1] : v2[2 * k];
            float oth  = hi ? v2[2 * k]     : v2[2 * k + 1];
            simk[k] = keep + __shfl_xor(oth, 4, 64);
        }
    }
    #pragma unroll
    for (int k = 0; k < 4; ++k) {
        int j = s + 8 * k;
        int rj = __shfl(rowj, j, 64);
        simk[k] = (rj >= 0) ? simk[k] * SCALEF : -FLT_MAX;
    }

    // ---- softmax over the 8-lane x 4-slot group ----
    float mx = fmaxf(fmaxf(simk[0], simk[1]), fmaxf(simk[2], simk[3]));
    mx = fmaxf(mx, __shfl_xor(mx, 1, 64));
    mx = fmaxf(mx, __shfl_xor(mx, 2, 64));
    mx = fmaxf(mx, __shfl_xor(mx, 4, 64));
    float att[4];
    float S = 0.f;
    #pragma unroll
    for (int k = 0; k < 4; ++k) { att[k] = __expf(simk[k] - mx); S += att[k]; }
    S += __shfl_xor(S, 1, 64);
    S += __shfl_xor(S, 2, 64);
    S += __shfl_xor(S, 4, 64);
    float inv = 1.f / S;
    #pragma unroll
    for (int k = 0; k < 4; ++k) att[k] *= inv;

    // ---- talking heads ----
    float wtg[8];
    #pragma unroll
    for (int hh = 0; hh < 8; ++hh) wtg[hh] = wtalk[h * 8 + hh];
    float pk[4];
    #pragma unroll
    for (int k = 0; k < 4; ++k) {
        float acc = 0.f;
        #pragma unroll
        for (int hh = 0; hh < 8; ++hh)
            acc += wtg[hh] * __shfl(att[k], hh * 8 + s, 64);
        pk[k] = acc;
    }

    // hoisted PV broadcasts (as packed pairs)
    floatx2 pj2[NNB];
    #pragma unroll
    for (int j = 0; j < NNB; ++j) {
        float pj = __shfl(pk[j >> 3], h * 8 + (j & 7), 64);
        pj2[j] = (floatx2){pj, pj};
    }

    // ---- PV, chunked 12/12/4 (packed fma) ----
    floatx2 o2[4];
    #pragma unroll
    for (int p = 0; p < 4; ++p) o2[p] = (floatx2){0.f, 0.f};
    #pragma unroll
    for (int j = 0; j < 12; ++j) {
        #pragma unroll
        for (int p = 0; p < 4; ++p)
            o2[p] = __builtin_elementwise_fma(pj2[j], up2(vc[j][p]), o2[p]);
    }
    #pragma unroll
    for (int j = 12; j < 24; ++j)
        vc[j - 12] = *(const uint4v*)&qkv[(size_t)rows[j] * QKVC + 1024 + lane * 8];
    #pragma unroll
    for (int j = 12; j < 24; ++j) {
        #pragma unroll
        for (int p = 0; p < 4; ++p)
            o2[p] = __builtin_elementwise_fma(pj2[j], up2(vc[j - 12][p]), o2[p]);
    }
    {
        uint4v vt_[4];
        #pragma unroll
        for (int j = 24; j < 28; ++j)
            vt_[j - 24] = *(const uint4v*)&qkv[(size_t)rows[j] * QKVC + 1024 + lane * 8];
        #pragma unroll
        for (int j = 24; j < 28; ++j) {
            #pragma unroll
            for (int p = 0; p < 4; ++p)
                o2[p] = __builtin_elementwise_fma(pj2[j], up2(vt_[j - 24][p]), o2[p]);
        }
    }

    ushort8v ov;
    #pragma unroll
    for (int p = 0; p < 4; ++p) {
        ov[2 * p]     = f2bf(o2[p].x);
        ov[2 * p + 1] = f2bf(o2[p].y);
    }
    *(ushort8v*)&outh[(size_t)(i + 1) * DIM + lane * 8] = ov;

    if (i == 0) {
        ushort8v bv = *(const ushort8v*)&qkv[1024 + lane * 8];
        *(ushort8v*)&outh[lane * 8] = bv;
    }
}

extern "C" void kernel_launch(void* const* d_in, const int* in_sizes, int n_in,
                              void* d_out, int out_size, void* d_ws, size_t ws_size,
                              hipStream_t stream) {
    const float* x     = (const float*)d_in[0];
    const float* wq    = (const float*)d_in[1];
    const float* wkv   = (const float*)d_in[2];
    const float* wtalk = (const float*)d_in[3];
    const float* wout  = (const float*)d_in[4];
    const float* bout  = (const float*)d_in[5];
    float* out = (float*)d_out;

    ushort_t* xb    = (ushort_t*)d_ws;                    // MPAD*512 bf16
    ushort_t* wcatT = xb    + (size_t)MPAD * 512;         // 1536*512
    ushort_t* woutT = wcatT + (size_t)QKVC * 512;         // 512*512
    ushort_t* qkv   = woutT + (size_t)512 * 512;          // MPAD*1536
    ushort_t* outh  = qkv   + (size_t)MPAD * QKVC;        // MPAD*512

    dim3 blk(256);
    conv_k<<<CONV_BLOCKS, blk, 0, stream>>>(x, wq, wkv, wout, xb, wcatT, woutT);
    gemm_k<64, 128, 128, false><<<dim3(12, 74), blk, 0, stream>>>(xb, wcatT, nullptr, qkv, QKVC);
    attn_k<<<dim3(NTOK / 4), blk, 0, stream>>>(qkv, wtalk, outh);
    gemm_k<64, 64, 64, true><<<dim3(8, 74), blk, 0, stream>>>(outh, woutT, bout, out, DIM);
}

// Round 15
// 46.005 us; speedup vs baseline: 1.0294x; 1.0294x over previous
//
#include <hip/hip_runtime.h>
#include <cfloat>
#include <cmath>

#define F_   8
#define H_   24
#define W_   24
#define NTOK 4608
#define NSEQ 4609
#define MPAD 4736           // 37*128 = 74*64
#define DIM  512
#define QKVC 1536           // q | k | v
#define NNB  28
#define SCALEF 0.125f

typedef unsigned short ushort_t;
typedef __attribute__((ext_vector_type(8))) short short8v;
typedef __attribute__((ext_vector_type(8))) unsigned short ushort8v;
typedef __attribute__((ext_vector_type(4))) float floatx4;
typedef __attribute__((ext_vector_type(2))) float floatx2;
typedef __attribute__((ext_vector_type(4))) unsigned int uint4v;

typedef const __attribute__((address_space(1))) unsigned int guint_t;
typedef __attribute__((address_space(3))) unsigned int luint_t;

__device__ __forceinline__ float bf2f(unsigned short u) {
    return __uint_as_float(((unsigned)u) << 16);
}
__device__ __forceinline__ unsigned short f2bf(float f) {
    unsigned u = __float_as_uint(f);
    unsigned r = (u + 0x7FFFu + ((u >> 16) & 1u)) >> 16;
    return (unsigned short)r;
}
// unpack u32 holding 2 bf16 (lo,hi) -> float2 {lo<<16, hi&0xffff0000}
__device__ __forceinline__ floatx2 up2(unsigned w) {
    floatx2 r;
    r.x = __uint_as_float(w << 16);
    r.y = __uint_as_float(w & 0xffff0000u);
    return r;
}

// ---------------------------------------------------------------------------
// Fused conversion (round-9 known-good):
//  blocks [0, XBLK):        x(f32) -> xb(bf16), rows zero-padded to MPAD
//  blocks [XBLK, XBLK+192): [w_q | w_kv] -> wcatT (bf16, [1536][512])
//  blocks [XBLK+192, +64):  w_out -> woutT (bf16, [512][512])
// ---------------------------------------------------------------------------
#define XBLK 1184                      // MPAD*512/2048
#define CONV_BLOCKS (XBLK + 192 + 64)

__global__ __launch_bounds__(256) void conv_k(
    const float* __restrict__ x, const float* __restrict__ wq,
    const float* __restrict__ wkv, const float* __restrict__ wout,
    ushort_t* __restrict__ xb, ushort_t* __restrict__ wcatT,
    ushort_t* __restrict__ woutT)
{
    const int bid = blockIdx.x, tid = threadIdx.x;
    __shared__ ushort_t tile[64][72];

    if (bid < XBLK) {
        int e0 = (bid * 256 + tid) * 8;
        int row = e0 >> 9;
        float4 a = make_float4(0.f, 0.f, 0.f, 0.f);
        float4 b = make_float4(0.f, 0.f, 0.f, 0.f);
        if (row < NSEQ) {
            a = *reinterpret_cast<const float4*>(&x[e0]);
            b = *reinterpret_cast<const float4*>(&x[e0 + 4]);
        }
        ushort8v o;
        o[0] = f2bf(a.x); o[1] = f2bf(a.y); o[2] = f2bf(a.z); o[3] = f2bf(a.w);
        o[4] = f2bf(b.x); o[5] = f2bf(b.y); o[6] = f2bf(b.z); o[7] = f2bf(b.w);
        *reinterpret_cast<ushort8v*>(&xb[e0]) = o;
        return;
    }

    int blk2 = bid - XBLK;
    const float* src; int ld, cb; ushort_t* dst; int k0;
    if (blk2 < 192) {
        int nt = blk2 >> 3, kt = blk2 & 7;
        int n0 = nt * 64;
        if (n0 < 512) { src = wq;  ld = 512;  cb = n0; }
        else          { src = wkv; ld = 1024; cb = n0 - 512; }
        dst = wcatT + (size_t)n0 * 512;
        k0 = kt * 64;
    } else {
        int b3 = blk2 - 192;
        int nt = b3 >> 3, kt = b3 & 7;
        src = wout; ld = 512; cb = nt * 64;
        dst = woutT + (size_t)(nt * 64) * 512;
        k0 = kt * 64;
    }

    {
        int r = tid >> 4, c4 = (tid & 15) * 4;
        #pragma unroll
        for (int p = 0; p < 4; ++p) {
            int rr = r + p * 16;
            float4 v = *reinterpret_cast<const float4*>(&src[(size_t)(k0 + rr) * ld + cb + c4]);
            tile[c4 + 0][rr] = f2bf(v.x);
            tile[c4 + 1][rr] = f2bf(v.y);
            tile[c4 + 2][rr] = f2bf(v.z);
            tile[c4 + 3][rr] = f2bf(v.w);
        }
    }
    __syncthreads();
    {
        int nl = tid >> 3, ks = (tid & 7) * 8;
        #pragma unroll
        for (int rep = 0; rep < 2; ++rep) {
            int nn = nl + rep * 32;
            ushort8v vv = *reinterpret_cast<const ushort8v*>(&tile[nn][ks]);
            *reinterpret_cast<ushort8v*>(&dst[(size_t)nn * 512 + k0 + ks]) = vv;
        }
    }
}

// ---------------------------------------------------------------------------
// bf16 MFMA GEMM, single-buffered (round-12/13 best-known), BK=64.
// stage(global_load_lds w16, XOR slot swizzle) -> barrier -> compute -> barrier
// Templated on BN: gemm_qkv BN=128 (12x74), gemm_out BN=64 (8x74).
// Bijective XCD-chunked block swizzle, __launch_bounds__(256,4).
// ---------------------------------------------------------------------------
template<int BM, int BN, bool F32OUT>
__global__ __launch_bounds__(256, 4) void gemm_k(
    const ushort_t* __restrict__ A,    // [MPAD][512] bf16
    const ushort_t* __restrict__ BT,   // [N][512] bf16
    const float* __restrict__ bias,
    void* __restrict__ Cv, int ldc)
{
    __shared__ ushort_t sA[BM * 64];
    __shared__ ushort_t sB[BN * 64];
    const int tid = threadIdx.x;

    const int nwg = gridDim.x * gridDim.y;
    const int orig = blockIdx.y * gridDim.x + blockIdx.x;
    const int xcd = orig & 7;
    const int qq = nwg >> 3, rr8 = nwg & 7;
    const int wg = (xcd < rr8 ? xcd * (qq + 1) : rr8 * (qq + 1) + (xcd - rr8) * qq)
                   + (orig >> 3);
    const int row0 = (wg / gridDim.x) * BM;
    const int col0 = (wg % gridDim.x) * BN;

    constexpr int NWC = BN / 64;       // wave-cols
    constexpr int NWR = 4 / NWC;       // wave-rows
    constexpr int WROWS = BM / NWR;    // rows per wave
    constexpr int MR = WROWS / 16;     // m-fragments per wave

    const int wid = tid >> 6, lane = tid & 63;
    const int wr = wid / NWC, wc = wid % NWC;
    const int l15 = lane & 15, kp = lane >> 4;

    floatx4 acc[MR][4];
    #pragma unroll
    for (int m = 0; m < MR; ++m)
        #pragma unroll
        for (int n = 0; n < 4; ++n)
            acc[m][n] = (floatx4){0.f, 0.f, 0.f, 0.f};

    const ushort_t* Abase = A + (size_t)row0 * 512;
    const ushort_t* Bbase = BT + (size_t)col0 * 512;

    for (int kt = 0; kt < 8; ++kt) {
        const int k0 = kt * 64;
        #pragma unroll
        for (int rnd = 0; rnd < BM / 32; ++rnd) {
            int r = rnd * 32 + (tid >> 3);
            int gs = (tid & 7) ^ (r & 7);
            __builtin_amdgcn_global_load_lds(
                (guint_t*)(Abase + (size_t)r * 512 + k0 + gs * 8),
                (luint_t*)(sA + r * 64 + (tid & 7) * 8), 16, 0, 0);
        }
        #pragma unroll
        for (int rnd = 0; rnd < BN / 32; ++rnd) {
            int r = rnd * 32 + (tid >> 3);
            int gs = (tid & 7) ^ (r & 7);
            __builtin_amdgcn_global_load_lds(
                (guint_t*)(Bbase + (size_t)r * 512 + k0 + gs * 8),
                (luint_t*)(sB + r * 64 + (tid & 7) * 8), 16, 0, 0);
        }
        __syncthreads();

        #pragma unroll
        for (int kk = 0; kk < 2; ++kk) {
            short8v af[MR], bfr[4];
            #pragma unroll
            for (int m = 0; m < MR; ++m) {
                int r = wr * WROWS + m * 16 + l15;
                int slot = kk * 4 + kp;
                af[m] = *(const short8v*)&sA[r * 64 + ((slot ^ (r & 7)) << 3)];
            }
            #pragma unroll
            for (int n = 0; n < 4; ++n) {
                int r = wc * 64 + n * 16 + l15;
                int slot = kk * 4 + kp;
                bfr[n] = *(const short8v*)&sB[r * 64 + ((slot ^ (r & 7)) << 3)];
            }
            #pragma unroll
            for (int m = 0; m < MR; ++m)
                #pragma unroll
                for (int n = 0; n < 4; ++n)
                    acc[m][n] = __builtin_amdgcn_mfma_f32_16x16x32_bf16(
                        af[m], bfr[n], acc[m][n], 0, 0, 0);
        }
        __syncthreads();
    }

    if (!F32OUT) {
        ushort_t* C = (ushort_t*)Cv;
        #pragma unroll
        for (int m = 0; m < MR; ++m) {
            int rb = row0 + wr * WROWS + m * 16 + kp * 4;
            #pragma unroll
            for (int n = 0; n < 4; ++n) {
                int col = col0 + wc * 64 + n * 16 + l15;
                #pragma unroll
                for (int q = 0; q < 4; ++q)
                    C[(size_t)(rb + q) * ldc + col] = f2bf(acc[m][n][q]);
            }
        }
    } else {
        float* C = (float*)Cv;
        #pragma unroll
        for (int m = 0; m < MR; ++m) {
            int rb = row0 + wr * WROWS + m * 16 + kp * 4;
            #pragma unroll
            for (int n = 0; n < 4; ++n) {
                int col = col0 + wc * 64 + n * 16 + l15;
                float bv = bias[col];
                #pragma unroll
                for (int q = 0; q < 4; ++q)
                    if (rb + q < NSEQ)
                        C[(size_t)(rb + q) * ldc + col] = acc[m][n][q] + bv;
            }
        }
    }
}

// ---------------------------------------------------------------------------
// Attention, wave-per-token (round-13 known-good): packed-fp32 math,
// chunked batched K loads, V chunk-1 prefetch under softmax, hoisted PV
// broadcasts, __launch_bounds__(256,4), XCD-chunked block swizzle.
// ---------------------------------------------------------------------------
__global__ __launch_bounds__(256, 4) void attn_k(
    const ushort_t* __restrict__ qkv,
    const float* __restrict__ wtalk,
    ushort_t* __restrict__ outh)
{
    const int lane = threadIdx.x & 63;
    const int bid0 = blockIdx.x;                            // 1152 = 8*144
    const int bswz = (bid0 & 7) * (gridDim.x >> 3) + (bid0 >> 3);
    const int i = bswz * 4 + (threadIdx.x >> 6);
    const int h = lane >> 3, s = lane & 7;

    const int t = i / (H_ * W_), rem = i % (H_ * W_);
    const int yy = rem / W_, xx = rem % W_;

    int rowj = -1;
    if (lane == 0) rowj = 0;
    else if (lane < NNB) {
        int e = lane - 1;
        int dt = e / 9 - 1, dy = (e / 3) % 3 - 1, dx = e % 3 - 1;
        int nt = t + dt, ny = yy + dy, nx = xx + dx;
        bool valid = ((unsigned)nt < (unsigned)F_) && ((unsigned)ny < (unsigned)H_) &&
                     ((unsigned)nx < (unsigned)W_);
        int u = (nt * H_ + ny) * W_ + nx;
        rowj = (valid && u <= i) ? (u + 1) : -1;
    }

    // clamped row table for loads (masked -> row 0)
    int rows[NNB];
    #pragma unroll
    for (int j = 0; j < NNB; ++j) {
        int r = __shfl(rowj, j, 64);
        rows[j] = r < 0 ? 0 : r;
    }

    // q as 4 packed float2 pairs
    floatx2 qf2[4];
    {
        uint4v qv = *(const uint4v*)&qkv[(size_t)(i + 1) * QKVC + lane * 8];
        #pragma unroll
        for (int p = 0; p < 4; ++p) qf2[p] = up2(qv[p]);
    }

    // ---- K dots, chunked 12/12/4 (batched loads, packed fma) ----
    float ps[NNB];
    {
        uint4v kc[12];
        #pragma unroll
        for (int j = 0; j < 12; ++j)
            kc[j] = *(const uint4v*)&qkv[(size_t)rows[j] * QKVC + 512 + lane * 8];
        #pragma unroll
        for (int j = 0; j < 12; ++j) {
            floatx2 a2 = (floatx2){0.f, 0.f};
            #pragma unroll
            for (int p = 0; p < 4; ++p)
                a2 = __builtin_elementwise_fma(qf2[p], up2(kc[j][p]), a2);
            ps[j] = a2.x + a2.y;
        }
        #pragma unroll
        for (int j = 12; j < 24; ++j)
            kc[j - 12] = *(const uint4v*)&qkv[(size_t)rows[j] * QKVC + 512 + lane * 8];
        #pragma unroll
        for (int j = 12; j < 24; ++j) {
            floatx2 a2 = (floatx2){0.f, 0.f};
            #pragma unroll
            for (int p = 0; p < 4; ++p)
                a2 = __builtin_elementwise_fma(qf2[p], up2(kc[j - 12][p]), a2);
            ps[j] = a2.x + a2.y;
        }
        uint4v kt_[4];
        #pragma unroll
        for (int j = 24; j < 28; ++j)
            kt_[j - 24] = *(const uint4v*)&qkv[(size_t)rows[j] * QKVC + 512 + lane * 8];
        #pragma unroll
        for (int j = 24; j < 28; ++j) {
            floatx2 a2 = (floatx2){0.f, 0.f};
            #pragma unroll
            for (int p = 0; p < 4; ++p)
                a2 = __builtin_elementwise_fma(qf2[p], up2(kt_[j - 24][p]), a2);
            ps[j] = a2.x + a2.y;
        }
    }

    // ---- V chunk-1 prefetch: in flight across reduce/softmax/TH ----
    uint4v vc[12];
    #pragma unroll
    for (int j = 0; j < 12; ++j)
        vc[j] = *(const uint4v*)&qkv[(size_t)rows[j] * QKVC + 1024 + lane * 8];

    // ---- reduce-scatter (xor 1,2,4) ----
    float v1[14];
    {
        bool hi = (s & 1) != 0;
        #pragma unroll
        for (int m = 0; m < 14; ++m) {
            float keep = hi ? ps[2 * m + 1] : ps[2 * m];
            float oth  = hi ? ps[2 * m]     : ps[2 * m + 1];
            v1[m] = keep + __shfl_xor(oth, 1, 64);
        }
    }
    float v2[8];
    {
        bool hi = (s & 2) != 0;
        #pragma unroll
        for (int m = 0; m < 7; ++m) {
            float keep = hi ? v1[2 * m + 1] : v1[2 * m];
            float oth  = hi ? v1[2 * m]     : v1[2 * m + 1];
            v2[m] = keep + __shfl_xor(oth, 2, 64);
        }
        v2[7] = 0.f;
    }
    float simk[4];
    {
        bool hi = (s & 4) != 0;
        #pragma unroll
        for (int k = 0; k < 4; ++k) {
            float keep = hi ? v2[2 * k + 1] : v2[2 * k];
            float oth  = hi ? v2[2 * k]     : v2[2 * k + 1];
            simk[k] = keep + __shfl_xor(oth, 4, 64);
        }
    }
    #pragma unroll
    for (int k = 0; k < 4; ++k) {
        int j = s + 8 * k;
        int rj = __shfl(rowj, j, 64);
        simk[k] = (rj >= 0) ? simk[k] * SCALEF : -FLT_MAX;
    }

    // ---- softmax over the 8-lane x 4-slot group ----
    float mx = fmaxf(fmaxf(simk[0], simk[1]), fmaxf(simk[2], simk[3]));
    mx = fmaxf(mx, __shfl_xor(mx, 1, 64));
    mx = fmaxf(mx, __shfl_xor(mx, 2, 64));
    mx = fmaxf(mx, __shfl_xor(mx, 4, 64));
    float att[4];
    float S = 0.f;
    #pragma unroll
    for (int k = 0; k < 4; ++k) { att[k] = __expf(simk[k] - mx); S += att[k]; }
    S += __shfl_xor(S, 1, 64);
    S += __shfl_xor(S, 2, 64);
    S += __shfl_xor(S, 4, 64);
    float inv = 1.f / S;
    #pragma unroll
    for (int k = 0; k < 4; ++k) att[k] *= inv;

    // ---- talking heads ----
    float wtg[8];
    #pragma unroll
    for (int hh = 0; hh < 8; ++hh) wtg[hh] = wtalk[h * 8 + hh];
    float pk[4];
    #pragma unroll
    for (int k = 0; k < 4; ++k) {
        float acc = 0.f;
        #pragma unroll
        for (int hh = 0; hh < 8; ++hh)
            acc += wtg[hh] * __shfl(att[k], hh * 8 + s, 64);
        pk[k] = acc;
    }

    // hoisted PV broadcasts (as packed pairs)
    floatx2 pj2[NNB];
    #pragma unroll
    for (int j = 0; j < NNB; ++j) {
        float pj = __shfl(pk[j >> 3], h * 8 + (j & 7), 64);
        pj2[j] = (floatx2){pj, pj};
    }

    // ---- PV, chunked 12/12/4 (packed fma) ----
    floatx2 o2[4];
    #pragma unroll
    for (int p = 0; p < 4; ++p) o2[p] = (floatx2){0.f, 0.f};
    #pragma unroll
    for (int j = 0; j < 12; ++j) {
        #pragma unroll
        for (int p = 0; p < 4; ++p)
            o2[p] = __builtin_elementwise_fma(pj2[j], up2(vc[j][p]), o2[p]);
    }
    #pragma unroll
    for (int j = 12; j < 24; ++j)
        vc[j - 12] = *(const uint4v*)&qkv[(size_t)rows[j] * QKVC + 1024 + lane * 8];
    #pragma unroll
    for (int j = 12; j < 24; ++j) {
        #pragma unroll
        for (int p = 0; p < 4; ++p)
            o2[p] = __builtin_elementwise_fma(pj2[j], up2(vc[j - 12][p]), o2[p]);
    }
    {
        uint4v vt_[4];
        #pragma unroll
        for (int j = 24; j < 28; ++j)
            vt_[j - 24] = *(const uint4v*)&qkv[(size_t)rows[j] * QKVC + 1024 + lane * 8];
        #pragma unroll
        for (int j = 24; j < 28; ++j) {
            #pragma unroll
            for (int p = 0; p < 4; ++p)
                o2[p] = __builtin_elementwise_fma(pj2[j], up2(vt_[j - 24][p]), o2[p]);
        }
    }

    ushort8v ov;
    #pragma unroll
    for (int p = 0; p < 4; ++p) {
        ov[2 * p]     = f2bf(o2[p].x);
        ov[2 * p + 1] = f2bf(o2[p].y);
    }
    *(ushort8v*)&outh[(size_t)(i + 1) * DIM + lane * 8] = ov;

    if (i == 0) {
        ushort8v bv = *(const ushort8v*)&qkv[1024 + lane * 8];
        *(ushort8v*)&outh[lane * 8] = bv;
    }
}

extern "C" void kernel_launch(void* const* d_in, const int* in_sizes, int n_in,
                              void* d_out, int out_size, void* d_ws, size_t ws_size,
                              hipStream_t stream) {
    const float* x     = (const float*)d_in[0];
    const float* wq    = (const float*)d_in[1];
    const float* wkv   = (const float*)d_in[2];
    const float* wtalk = (const float*)d_in[3];
    const float* wout  = (const float*)d_in[4];
    const float* bout  = (const float*)d_in[5];
    float* out = (float*)d_out;

    ushort_t* xb    = (ushort_t*)d_ws;                    // MPAD*512 bf16
    ushort_t* wcatT = xb    + (size_t)MPAD * 512;         // 1536*512
    ushort_t* woutT = wcatT + (size_t)QKVC * 512;         // 512*512
    ushort_t* qkv   = woutT + (size_t)512 * 512;          // MPAD*1536
    ushort_t* outh  = qkv   + (size_t)MPAD * QKVC;        // MPAD*512

    dim3 blk(256);
    conv_k<<<CONV_BLOCKS, blk, 0, stream>>>(x, wq, wkv, wout, xb, wcatT, woutT);
    gemm_k<64, 128, false><<<dim3(12, 74), blk, 0, stream>>>(xb, wcatT, nullptr, qkv, QKVC);
    attn_k<<<dim3(NTOK / 4), blk, 0, stream>>>(qkv, wtalk, outh);
    gemm_k<64, 64, true><<<dim3(8, 74), blk, 0, stream>>>(outh, woutT, bout, out, DIM);
}